// Round 1
// baseline (21.265 us; speedup 1.0000x reference)
//
#include <hip/hip_runtime.h>

// Helmholtz loss reduced form:
//   patch(b,h,w) = w_vec^T H w_vec,  w_vec from 5 linear per-pixel fields F1..F5
// See derivation in session notes: quad(C) = r^T C r with r = colsum(M Q M^T),
// r = M (Q^T u), u = colsum(M); qC3T == qC3 as scalars.

struct HParams {
    float u0, u1, u2, u3;
    float Hs[4][4];
};

#define ROWS_PER_TILE 8
#define NTILES 64            // ceil(511/8)
#define BSIZE 256

__global__ __launch_bounds__(BSIZE) void helm_main(const float* __restrict__ x,
                                                   double* __restrict__ partial,
                                                   HParams P)
{
    const int bid  = blockIdx.x;
    const int b    = bid >> 6;          // / NTILES
    const int tile = bid & 63;
    const int h0   = tile * ROWS_PER_TILE;
    const int rend = min(h0 + ROWS_PER_TILE, 511);   // data rows h0..rend, patch rows h0..rend-1
    const int t    = threadIdx.x;

    __shared__ float raw[4][512];          // one data row, 4 channels
    __shared__ float buf[2][5][512];       // F1,F2,F3,F4,F5 double-buffered by row parity
    __shared__ double wsum[4];

    const float* xb = x + (size_t)b * 4u * 512u * 512u;

    // float4 load mapping: flat = t (+256); c = flat>>7, q = flat&127
    const int c0 = t >> 7;          // 0..1
    const int c1 = 2 + (t >> 7);    // 2..3
    const int q  = t & 127;
    const float4* p0 = (const float4*)(xb + (size_t)c0 * 262144u) + q;
    const float4* p1 = (const float4*)(xb + (size_t)c1 * 262144u) + q;

    double acc = 0.0;

    float4 r0 = p0[(size_t)h0 * 128u];
    float4 r1 = p1[(size_t)h0 * 128u];

    for (int r = h0; r <= rend; ++r) {
        // stage current row into LDS (waits on the prefetched loads)
        ((float4*)raw[c0])[q] = r0;
        ((float4*)raw[c1])[q] = r1;
        // prefetch next row (stays in flight across the syncs below)
        float4 n0 = make_float4(0.f, 0.f, 0.f, 0.f);
        float4 n1 = make_float4(0.f, 0.f, 0.f, 0.f);
        if (r < rend) {
            n0 = p0[(size_t)(r + 1) * 128u];
            n1 = p1[(size_t)(r + 1) * 128u];
        }
        __syncthreads();

        // compute F fields for this row, columns t and t+256
        {
            float (*bw)[512] = buf[r & 1];
            #pragma unroll
            for (int k = 0; k < 2; ++k) {
                const int w = t + k * 256;
                const float x0 = raw[0][w];
                const float x1 = raw[1][w];
                const float x2 = raw[2][w];
                const float x3 = raw[3][w];
                bw[0][w] = P.u0 * x0 + P.u2 * x3;   // F1: top part of w0
                bw[1][w] = P.u0 * x0 + P.u2 * x1;   // F2: top part of w1
                bw[2][w] = P.u1 * x0 + P.u3 * x1;   // F3: bottom part of w0,w1
                bw[3][w] = P.u0 * x2 + P.u2 * x3;   // F4: top part of w2,w3
                bw[4][w] = P.u1 * x2 + P.u3 * x3;   // F5: bottom part of w2,w3
            }
        }
        __syncthreads();

        // patches of row r-1 use top fields (row r-1) + bottom fields (row r)
        if (r > h0) {
            const float (*bt)[512] = buf[(r - 1) & 1];
            const float (*bb)[512] = buf[r & 1];
            #pragma unroll
            for (int k = 0; k < 2; ++k) {
                const int w = t + k * 256;
                if (w < 511) {
                    const float w0 = bt[0][w]     + bb[2][w];
                    const float w1 = bt[1][w + 1] + bb[2][w + 1];
                    const float w2 = bt[3][w]     + bb[4][w];
                    const float w3 = bt[3][w + 1] + bb[4][w + 1];
                    const float t0 = P.Hs[0][0]*w0 + P.Hs[0][1]*w1 + P.Hs[0][2]*w2 + P.Hs[0][3]*w3;
                    const float t1 = P.Hs[1][0]*w0 + P.Hs[1][1]*w1 + P.Hs[1][2]*w2 + P.Hs[1][3]*w3;
                    const float t2 = P.Hs[2][0]*w0 + P.Hs[2][1]*w1 + P.Hs[2][2]*w2 + P.Hs[2][3]*w3;
                    const float t3 = P.Hs[3][0]*w0 + P.Hs[3][1]*w1 + P.Hs[3][2]*w2 + P.Hs[3][3]*w3;
                    acc += (double)(w0 * t0 + w1 * t1 + w2 * t2 + w3 * t3);
                }
            }
        }
        __syncthreads();

        r0 = n0;
        r1 = n1;
    }

    // block reduction (4 waves of 64)
    for (int off = 32; off > 0; off >>= 1)
        acc += __shfl_down(acc, off, 64);
    const int lane = t & 63;
    const int wid  = t >> 6;
    if (lane == 0) wsum[wid] = acc;
    __syncthreads();
    if (t == 0)
        partial[bid] = wsum[0] + wsum[1] + wsum[2] + wsum[3];
}

__global__ __launch_bounds__(BSIZE) void helm_reduce(const double* __restrict__ partial,
                                                     float* __restrict__ out, int n)
{
    __shared__ double wsum[4];
    const int t = threadIdx.x;
    double a = 0.0;
    for (int i = t; i < n; i += BSIZE) a += partial[i];
    for (int off = 32; off > 0; off >>= 1)
        a += __shfl_down(a, off, 64);
    if ((t & 63) == 0) wsum[t >> 6] = a;
    __syncthreads();
    if (t == 0) {
        const double sum = wsum[0] + wsum[1] + wsum[2] + wsum[3];
        out[0] = (float)(sum / (16.0 * 511.0 * 511.0));
    }
}

extern "C" void kernel_launch(void* const* d_in, const int* in_sizes, int n_in,
                              void* d_out, int out_size, void* d_ws, size_t ws_size,
                              hipStream_t stream) {
    const float* x = (const float*)d_in[0];
    float* out     = (float*)d_out;
    double* partial = (double*)d_ws;     // 1024 doubles = 8 KB

    // ---- host-side constant computation (double precision) ----
    const double L = 0.01;
    double lm[7];
    lm[0] = L;
    for (int i = 1; i < 7; ++i) lm[i] = lm[i - 1] * L;

    double C1[4][4], C2[4][4] = {}, C3[4][4] = {};
    for (int i = 0; i < 4; ++i)
        for (int j = 0; j < 4; ++j)
            C1[i][j] = lm[i + j] / (double)(i + j + 1);
    C2[2][2] = 4.0 * lm[0];  C2[2][3] = 6.0 * lm[1];
    C2[3][2] = 6.0 * lm[1];  C2[3][3] = 12.0 * lm[2];
    C3[2][0] = 2.0 * lm[0];  C3[2][1] = lm[1];
    C3[2][2] = (2.0 / 3.0) * lm[2];  C3[2][3] = 0.5 * lm[3];
    C3[3][0] = 3.0 * lm[1];  C3[3][1] = 2.0 * lm[2];
    C3[3][2] = 1.5 * lm[3];  C3[3][3] = (6.0 / 5.0) * lm[4];

    const double M[4][4] = {
        {1.0, 0.0, 0.0, 0.0},
        {0.0, 0.0, 1.0, 0.0},
        {-3.0 / lm[1], 3.0 / lm[1], -2.0 / lm[0], -1.0 / lm[0]},
        { 2.0 / lm[2], -2.0 / lm[2], 1.0 / lm[1],  1.0 / lm[1]}
    };

    double s1 = 0.0, s2 = 0.0, s3 = 0.0;
    for (int i = 0; i < 4; ++i)
        for (int j = 0; j < 4; ++j) {
            s1 += C1[i][j]; s2 += C2[i][j]; s3 += C3[i][j];
        }

    const double k2 = 20.0 * 20.0;   // K*K
    const double a1 = s2 + k2 * k2 * s1 + 2.0 * k2 * s3;  // coeff of qC1
    const double a2 = s1;                                 // coeff of qC2
    const double a3 = 2.0 * s3 + 2.0 * k2 * s1;           // coeff of qC3 (incl. qC3T == qC3)

    double G[4][4];
    for (int i = 0; i < 4; ++i)
        for (int j = 0; j < 4; ++j)
            G[i][j] = a1 * C1[i][j] + a2 * C2[i][j] + a3 * C3[i][j];

    double H[4][4] = {};
    for (int jj = 0; jj < 4; ++jj)
        for (int kk = 0; kk < 4; ++kk) {
            double s = 0.0;
            for (int a = 0; a < 4; ++a)
                for (int bb = 0; bb < 4; ++bb)
                    s += M[a][jj] * G[a][bb] * M[bb][kk];
            H[jj][kk] = s;
        }

    HParams P;
    double u[4];
    for (int j = 0; j < 4; ++j) {
        u[j] = M[0][j] + M[1][j] + M[2][j] + M[3][j];
    }
    P.u0 = (float)u[0]; P.u1 = (float)u[1]; P.u2 = (float)u[2]; P.u3 = (float)u[3];
    for (int jj = 0; jj < 4; ++jj)
        for (int kk = 0; kk < 4; ++kk)
            P.Hs[jj][kk] = (float)(0.5 * (H[jj][kk] + H[kk][jj]));

    (void)in_sizes; (void)n_in; (void)out_size; (void)ws_size;

    helm_main<<<dim3(16 * NTILES), dim3(BSIZE), 0, stream>>>(x, partial, P);
    helm_reduce<<<dim3(1), dim3(BSIZE), 0, stream>>>(partial, out, 16 * NTILES);
}

// Round 2
// 19.764 us; speedup vs baseline: 1.0759x; 1.0759x over previous
//
#include <hip/hip_runtime.h>

// Helmholtz loss, fully reduced:
//   patch(b,h,w) = w_vec^T H w_vec, w_vec from 5 per-pixel linear fields,
//   H = M^T (a1*C1 + a2*C2 + a3*C3sym) M  (symmetrized, host-computed in double)
// Register-streaming stencil: one wave per 8-row strip, no LDS, no barriers.

struct HParams {
    float u0, u1, u2, u3;
    float H00, H11, H22, H33;
    float H01_2, H02_2, H03_2, H12_2, H13_2, H23_2;
};

#define BSIZE 256

__device__ __forceinline__ float f4get(const float4& v, int k) {
    switch (k & 3) { case 0: return v.x; case 1: return v.y; case 2: return v.z; default: return v.w; }
}

struct Fields { float f1[8], f2[8], f3[8], f4[8], f5[8]; };

#define LOADROW(B, r) do {                                                  \
    _Pragma("unroll")                                                       \
    for (int ch = 0; ch < 4; ++ch) {                                        \
        const size_t base_ = (size_t)ch * 65536u + (size_t)(r) * 128u + cq; \
        B[2*ch]   = px[base_];                                              \
        B[2*ch+1] = px[base_ + 1];                                          \
    } } while (0)

#define FIELDS(F, B) do {                                                   \
    _Pragma("unroll")                                                       \
    for (int j = 0; j < 8; ++j) {                                           \
        const float x0_ = f4get(B[0 + (j>>2)], j);                          \
        const float x1_ = f4get(B[2 + (j>>2)], j);                          \
        const float x2_ = f4get(B[4 + (j>>2)], j);                          \
        const float x3_ = f4get(B[6 + (j>>2)], j);                          \
        const float t0_ = P.u0 * x0_;                                       \
        F.f1[j] = fmaf(P.u2, x3_, t0_);                                     \
        F.f2[j] = fmaf(P.u2, x1_, t0_);                                     \
        F.f3[j] = fmaf(P.u3, x1_, P.u1 * x0_);                              \
        F.f4[j] = fmaf(P.u2, x3_, P.u0 * x2_);                              \
        F.f5[j] = fmaf(P.u3, x3_, P.u1 * x2_);                              \
    } } while (0)

// Ft = top-row fields, Fb = bottom-row fields; accumulates into acc.
#define PATCH(Ft, Fb) do {                                                  \
    float aV[8], bV[8], cV[8];                                              \
    _Pragma("unroll")                                                       \
    for (int j = 0; j < 8; ++j) {                                           \
        aV[j] = Ft.f1[j] + Fb.f3[j];                                        \
        bV[j] = Ft.f2[j] + Fb.f3[j];                                        \
        cV[j] = Ft.f4[j] + Fb.f5[j];                                        \
    }                                                                       \
    const float bn_ = __shfl_down(bV[0], 1, 64);                            \
    const float cn_ = __shfl_down(cV[0], 1, 64);                            \
    float rowsum_ = 0.0f;                                                   \
    _Pragma("unroll")                                                       \
    for (int j = 0; j < 8; ++j) {                                           \
        const float w0_ = aV[j];                                            \
        const float w1_ = (j < 7) ? bV[j+1] : bn_;                          \
        const float w2_ = cV[j];                                            \
        const float w3_ = (j < 7) ? cV[j+1] : cn_;                          \
        const float q0_ = fmaf(P.H03_2, w3_, fmaf(P.H02_2, w2_, fmaf(P.H01_2, w1_, P.H00 * w0_))); \
        const float q1_ = fmaf(P.H13_2, w3_, fmaf(P.H12_2, w2_, P.H11 * w1_)); \
        const float q2_ = fmaf(P.H23_2, w3_, P.H22 * w2_);                  \
        const float q3_ = P.H33 * w3_;                                      \
        const float pq_ = fmaf(w0_, q0_, fmaf(w1_, q1_, fmaf(w2_, q2_, w3_ * q3_))); \
        if (j < 7 || lane < 63) rowsum_ += pq_;                             \
    }                                                                       \
    acc += (double)rowsum_;                                                 \
} while (0)

__global__ __launch_bounds__(BSIZE) void helm_main(const float* __restrict__ x,
                                                   double* __restrict__ partial,
                                                   HParams P)
{
    const int t    = threadIdx.x;
    const int lane = t & 63;
    const int wid  = t >> 6;
    const int sid  = blockIdx.x * 4 + wid;   // 0..1023 wave-strips
    const int b    = sid >> 6;               // image 0..15
    const int tile = sid & 63;               // strip 0..63
    const int h0   = tile * 8;
    const int hend = min(h0 + 8, 511);       // last data row of strip

    const float4* px = (const float4*)(x + (size_t)b * (4u * 512u * 512u));
    const int cq = lane * 2;                 // float4 index of lane's 8-col base

    float4 A0[8], A1[8];
    Fields Fa, Fb;
    double acc = 0.0;

    LOADROW(A0, h0);
    LOADROW(A1, h0 + 1);
    FIELDS(Fa, A0);

    int r = h0 + 1;
    while (true) {
        // cur row r is in A1 -> Fb
        if (r + 1 <= hend) LOADROW(A0, r + 1);
        FIELDS(Fb, A1);
        PATCH(Fa, Fb);
        ++r; if (r > hend) break;
        // cur row r is in A0 -> Fa
        if (r + 1 <= hend) LOADROW(A1, r + 1);
        FIELDS(Fa, A0);
        PATCH(Fb, Fa);
        ++r; if (r > hend) break;
    }

    // wave reduction (f64 shuffles), one double per wave-strip
    #pragma unroll
    for (int off = 32; off > 0; off >>= 1)
        acc += __shfl_down(acc, off, 64);
    if (lane == 0) partial[sid] = acc;
}

__global__ __launch_bounds__(BSIZE) void helm_reduce(const double* __restrict__ partial,
                                                     float* __restrict__ out, int n)
{
    __shared__ double wsum[4];
    const int t = threadIdx.x;
    double a = 0.0;
    for (int i = t; i < n; i += BSIZE) a += partial[i];
    #pragma unroll
    for (int off = 32; off > 0; off >>= 1)
        a += __shfl_down(a, off, 64);
    if ((t & 63) == 0) wsum[t >> 6] = a;
    __syncthreads();
    if (t == 0) {
        const double sum = wsum[0] + wsum[1] + wsum[2] + wsum[3];
        out[0] = (float)(sum / (16.0 * 511.0 * 511.0));
    }
}

extern "C" void kernel_launch(void* const* d_in, const int* in_sizes, int n_in,
                              void* d_out, int out_size, void* d_ws, size_t ws_size,
                              hipStream_t stream) {
    const float* x  = (const float*)d_in[0];
    float* out      = (float*)d_out;
    double* partial = (double*)d_ws;     // 1024 doubles = 8 KB

    // ---- host-side constant computation (double precision) ----
    const double L = 0.01;
    double lm[7];
    lm[0] = L;
    for (int i = 1; i < 7; ++i) lm[i] = lm[i - 1] * L;

    double C1[4][4], C2[4][4] = {}, C3[4][4] = {};
    for (int i = 0; i < 4; ++i)
        for (int j = 0; j < 4; ++j)
            C1[i][j] = lm[i + j] / (double)(i + j + 1);
    C2[2][2] = 4.0 * lm[0];  C2[2][3] = 6.0 * lm[1];
    C2[3][2] = 6.0 * lm[1];  C2[3][3] = 12.0 * lm[2];
    C3[2][0] = 2.0 * lm[0];  C3[2][1] = lm[1];
    C3[2][2] = (2.0 / 3.0) * lm[2];  C3[2][3] = 0.5 * lm[3];
    C3[3][0] = 3.0 * lm[1];  C3[3][1] = 2.0 * lm[2];
    C3[3][2] = 1.5 * lm[3];  C3[3][3] = (6.0 / 5.0) * lm[4];

    const double M[4][4] = {
        {1.0, 0.0, 0.0, 0.0},
        {0.0, 0.0, 1.0, 0.0},
        {-3.0 / lm[1], 3.0 / lm[1], -2.0 / lm[0], -1.0 / lm[0]},
        { 2.0 / lm[2], -2.0 / lm[2], 1.0 / lm[1],  1.0 / lm[1]}
    };

    double s1 = 0.0, s2 = 0.0, s3 = 0.0;
    for (int i = 0; i < 4; ++i)
        for (int j = 0; j < 4; ++j) {
            s1 += C1[i][j]; s2 += C2[i][j]; s3 += C3[i][j];
        }

    const double k2 = 20.0 * 20.0;   // K*K
    const double a1 = s2 + k2 * k2 * s1 + 2.0 * k2 * s3;  // coeff of qC1
    const double a2 = s1;                                 // coeff of qC2
    const double a3 = 2.0 * s3 + 2.0 * k2 * s1;           // coeff of qC3 (+ qC3T == qC3)

    double G[4][4];
    for (int i = 0; i < 4; ++i)
        for (int j = 0; j < 4; ++j)
            G[i][j] = a1 * C1[i][j] + a2 * C2[i][j] + a3 * C3[i][j];

    double H[4][4] = {};
    for (int jj = 0; jj < 4; ++jj)
        for (int kk = 0; kk < 4; ++kk) {
            double s = 0.0;
            for (int a = 0; a < 4; ++a)
                for (int bb = 0; bb < 4; ++bb)
                    s += M[a][jj] * G[a][bb] * M[bb][kk];
            H[jj][kk] = s;
        }
    // symmetrize
    double Hs[4][4];
    for (int i = 0; i < 4; ++i)
        for (int j = 0; j < 4; ++j)
            Hs[i][j] = 0.5 * (H[i][j] + H[j][i]);

    double u[4];
    for (int j = 0; j < 4; ++j)
        u[j] = M[0][j] + M[1][j] + M[2][j] + M[3][j];

    HParams P;
    P.u0 = (float)u[0]; P.u1 = (float)u[1]; P.u2 = (float)u[2]; P.u3 = (float)u[3];
    P.H00 = (float)Hs[0][0]; P.H11 = (float)Hs[1][1];
    P.H22 = (float)Hs[2][2]; P.H33 = (float)Hs[3][3];
    P.H01_2 = (float)(2.0 * Hs[0][1]); P.H02_2 = (float)(2.0 * Hs[0][2]);
    P.H03_2 = (float)(2.0 * Hs[0][3]); P.H12_2 = (float)(2.0 * Hs[1][2]);
    P.H13_2 = (float)(2.0 * Hs[1][3]); P.H23_2 = (float)(2.0 * Hs[2][3]);

    (void)in_sizes; (void)n_in; (void)out_size; (void)ws_size;

    helm_main<<<dim3(256), dim3(BSIZE), 0, stream>>>(x, partial, P);
    helm_reduce<<<dim3(1), dim3(BSIZE), 0, stream>>>(partial, out, 1024);
}